// Round 26
// baseline (61.386 us; speedup 1.0000x reference)
//
#include <hip/hip_runtime.h>

typedef float v2f __attribute__((ext_vector_type(2)));
typedef float v4f __attribute__((ext_vector_type(4)));
typedef __fp16 h2 __attribute__((ext_vector_type(2)));
typedef __fp16 h4 __attribute__((ext_vector_type(4)));

#define B_ 64
#define T_ 2048
#define D_ 512
#define K_ 8
#define THREADS 256
#define TILE_R 32
#define XPITCH 520   // f16 pitch: 512 + 8 pad
#define LGP 9        // logits pitch (f32)
#define APITCH 12    // a-table pitch (f32)
#define LOG2E 1.44269504088896340736f

// Raw barrier discipline (T3/T4): __syncthreads() drains vmcnt(0) before
// s_barrier -- keeps prefetch loads in flight across barriers instead.
#define LGKM0 asm volatile("s_waitcnt lgkmcnt(0)" ::: "memory")
#define BARRIER __builtin_amdgcn_s_barrier()
#define PIN __builtin_amdgcn_sched_barrier(0)

__device__ __forceinline__ float dev_exp2(float v) { return __builtin_amdgcn_exp2f(v); }
__device__ __forceinline__ h2 pack2(float a, float b) { return __builtin_amdgcn_cvt_pkrtz(a, b); }

// Round 26: the last untested occupancy point. R24's cap@128 (4 blocks/CU)
// spilled; R22 unconstrained (~140 VGPR) sits at 2 blocks/CU. Intermediate:
// __launch_bounds__(256,3) -> VGPR cap ~170 (fits ~140, no spill expected),
// 3 resident blocks/CU. Paired with NCHUNK=16 (1024 blocks = 4/CU of work)
// so the extra residency is usable. Trade: TILES 8->4 (worse prologue
// amortization) vs +50% overlap for the phase-serial chain. If this
// regresses, R25 (56.4us) stands and the structure is at its roofline.
template <int NCHUNK_T>
__global__ __launch_bounds__(THREADS, 3) void k1_accum(
    const float* __restrict__ x, const float* __restrict__ attn_w,
    const float* __restrict__ attn_b, float* __restrict__ ax_part,
    float* __restrict__ asum_part) {
  constexpr int RPC = T_ / NCHUNK_T;
  constexpr int TILES = RPC / TILE_R;  // 4 (NCHUNK=16) or 8 (NCHUNK=8)

  const int blk = blockIdx.x;
  const int b = blk / NCHUNK_T;
  const int chunk = blk % NCHUNK_T;
  const int tid = threadIdx.x;
  const int wave = tid >> 6;
  const int lane = tid & 63;

  __shared__ __align__(16) __fp16 xt[TILE_R * XPITCH];  // 33.3 KB
  __shared__ float lg[4 * TILE_R * LGP];                // 4.6 KB
  __shared__ __align__(16) float at[TILE_R * APITCH];   // 1.5 KB
  __shared__ float bt[K_];

  if (tid < K_) bt[tid] = attn_b[tid] * LOG2E;

  // MFMA lane constants (layout verified on-silicon R13/R18/R20):
  //   A[m][k]: m=lane&15, k=(lane>>4)*4+i ; B[k][n]: n=lane&15, same k
  //   C[m][n]: n=lane&15, m=(lane>>4)*4+j
  const int m16 = lane & 15;
  const int kgrp = lane >> 4;
  const int koff = wave * 128 + kgrp * 4;  // wave owns a 128-d K-quarter
  const __fp16* arow0 = xt + m16 * XPITCH + koff;
  const __fp16* arow1 = xt + (16 + m16) * XPITCH + koff;

  const int d0p2 = wave * 128 + lane * 2;  // pass2 d-pair ownership

  v2f acc[K_];
#pragma unroll
  for (int k = 0; k < K_; ++k) acc[k] = (v2f){0.f, 0.f};
  float asum[K_];
#pragma unroll
  for (int k = 0; k < K_; ++k) asum[k] = 0.f;

  const float* xbase = x + ((size_t)b * T_ + (size_t)chunk * RPC) * (size_t)D_;
  const int t4 = tid << 2;

  float4 f0, f1, f2, f3, f4, f5, f6, f7, f8, f9, f10, f11, f12, f13, f14, f15;
#define LOADT(tt)                                                    \
  do {                                                               \
    const float* s_ = xbase + (size_t)(tt) * TILE_R * D_ + t4;       \
    f0 = *(const float4*)(s_ + 0 * 1024);                            \
    f1 = *(const float4*)(s_ + 1 * 1024);                            \
    f2 = *(const float4*)(s_ + 2 * 1024);                            \
    f3 = *(const float4*)(s_ + 3 * 1024);                            \
    f4 = *(const float4*)(s_ + 4 * 1024);                            \
    f5 = *(const float4*)(s_ + 5 * 1024);                            \
    f6 = *(const float4*)(s_ + 6 * 1024);                            \
    f7 = *(const float4*)(s_ + 7 * 1024);                            \
    f8 = *(const float4*)(s_ + 8 * 1024);                            \
    f9 = *(const float4*)(s_ + 9 * 1024);                            \
    f10 = *(const float4*)(s_ + 10 * 1024);                          \
    f11 = *(const float4*)(s_ + 11 * 1024);                          \
    f12 = *(const float4*)(s_ + 12 * 1024);                          \
    f13 = *(const float4*)(s_ + 13 * 1024);                          \
    f14 = *(const float4*)(s_ + 14 * 1024);                          \
    f15 = *(const float4*)(s_ + 15 * 1024);                          \
  } while (0)
#define WRT1(i, F)                                                   \
  do {                                                               \
    const int g_ = (i)*1024 + t4;                                    \
    const h2 lo_ = pack2(F.x, F.y), hi_ = pack2(F.z, F.w);           \
    h4 v_;                                                           \
    v_[0] = lo_[0]; v_[1] = lo_[1]; v_[2] = hi_[0]; v_[3] = hi_[1];  \
    *(h4*)(xt + (g_ >> 9) * XPITCH + (g_ & 511)) = v_;               \
  } while (0)
#define WRITET()                                                     \
  do {                                                               \
    WRT1(0, f0); WRT1(1, f1); WRT1(2, f2); WRT1(3, f3);              \
    WRT1(4, f4); WRT1(5, f5); WRT1(6, f6); WRT1(7, f7);              \
    WRT1(8, f8); WRT1(9, f9); WRT1(10, f10); WRT1(11, f11);          \
    WRT1(12, f12); WRT1(13, f13); WRT1(14, f14); WRT1(15, f15);      \
  } while (0)

  // prologue: stage tile0; B-frags from GLOBAL (W L2-hot, once per block);
  // issue tile1 (stays in flight across barriers, un-drained)
  LOADT(0);
  WRITET();
  h4 bf[8];
  {
    const int wrow = (m16 < K_ ? m16 : (K_ - 1));  // clamp pad cols
    const float* wg = attn_w + wrow * D_ + koff;
#pragma unroll
    for (int s = 0; s < 8; ++s) {
      const float4 g = *(const float4*)(wg + s * 16);
      const h2 lo = pack2(g.x * LOG2E, g.y * LOG2E);
      const h2 hi = pack2(g.z * LOG2E, g.w * LOG2E);
      bf[s][0] = lo[0]; bf[s][1] = lo[1]; bf[s][2] = hi[0]; bf[s][3] = hi[1];
    }
  }
  LOADT(1);
  PIN;  // pin tile1 issue point
  LGKM0;
  BARRIER;  // xt(0) + bt visible; tile1 loads in flight

#pragma unroll
  for (int t = 0; t < TILES; ++t) {
    // ---- pass1: logits = X·W^T via MFMA (A from xt, B from regs)
    {
      v4f c0 = {0.f, 0.f, 0.f, 0.f}, c1 = {0.f, 0.f, 0.f, 0.f};
#pragma unroll
      for (int s = 0; s < 8; ++s) {
        const h4 a0 = *(const h4*)(arow0 + s * 16);
        const h4 a1 = *(const h4*)(arow1 + s * 16);
        c0 = __builtin_amdgcn_mfma_f32_16x16x16f16(a0, bf[s], c0, 0, 0, 0);
        c1 = __builtin_amdgcn_mfma_f32_16x16x16f16(a1, bf[s], c1, 0, 0, 0);
      }
      if (m16 < K_) {
        const int base = (wave * TILE_R + kgrp * 4) * LGP + m16;
#pragma unroll
        for (int j = 0; j < 4; ++j) {
          lg[base + j * LGP] = c0[j];
          lg[base + (16 + j) * LGP] = c1[j];
        }
      }
    }
    LGKM0;
    BARRIER;  // lg visible

    // ---- softmax: lane-per-row (exp2 domain, no max-sub: logits ~N(0,1),
    //      fp32-safe; ratio identical). asum accumulated per owning lane.
    if (wave == 0 && lane < TILE_R) {
      float e[K_];
      float tot = 0.f;
#pragma unroll
      for (int k = 0; k < K_; ++k) {
        const float l = ((lg[(0 * TILE_R + lane) * LGP + k] +
                          lg[(1 * TILE_R + lane) * LGP + k]) +
                         (lg[(2 * TILE_R + lane) * LGP + k] +
                          lg[(3 * TILE_R + lane) * LGP + k])) + bt[k];
        e[k] = dev_exp2(l);
        tot += e[k];
      }
      const float inv = __builtin_amdgcn_rcpf(tot);
      float4* ad = (float4*)(at + lane * APITCH);
      ad[0] = (float4){e[0] * inv, e[1] * inv, e[2] * inv, e[3] * inv};
      ad[1] = (float4){e[4] * inv, e[5] * inv, e[6] * inv, e[7] * inv};
#pragma unroll
      for (int k = 0; k < K_; ++k) asum[k] += e[k] * inv;
    }
    LGKM0;
    BARRIER;  // at visible

    // ---- pass2: acc[k] += a[r][k] * x[r][d-pair]; a broadcast, x b32
#pragma unroll 4
    for (int rr = 0; rr < TILE_R; ++rr) {
      const float4 alo = *(const float4*)(at + rr * APITCH);
      const float4 ahi = *(const float4*)(at + rr * APITCH + 4);
      const h2 xp = *(const h2*)(xt + rr * XPITCH + d0p2);
      const v2f xv = {(float)xp[0], (float)xp[1]};
      acc[0] += (v2f){alo.x, alo.x} * xv;
      acc[1] += (v2f){alo.y, alo.y} * xv;
      acc[2] += (v2f){alo.z, alo.z} * xv;
      acc[3] += (v2f){alo.w, alo.w} * xv;
      acc[4] += (v2f){ahi.x, ahi.x} * xv;
      acc[5] += (v2f){ahi.y, ahi.y} * xv;
      acc[6] += (v2f){ahi.z, ahi.z} * xv;
      acc[7] += (v2f){ahi.w, ahi.w} * xv;
    }
    LGKM0;
    BARRIER;  // all waves done reading xt(t)

    // ---- drain tile t+1 into xt (loads issued a full iter ago: covered);
    //      issue tile t+2 (covered by next iter's pass1..pass2)
    if (t + 1 < TILES) {
      WRITET();
      if (t + 2 < TILES) {
        LOADT(t + 2);
        PIN;
      }
      LGKM0;
      BARRIER;  // xt(t+1) visible
    }
  }
#undef LOADT
#undef WRT1
#undef WRITET

  // ---- write per-chunk partials
  float* outp = ax_part + (size_t)blk * (K_ * D_);
#pragma unroll
  for (int k = 0; k < K_; ++k) *(v2f*)(outp + k * D_ + d0p2) = acc[k];
  // asum: reduce across the 32 row-owning lanes of wave 0
  if (wave == 0 && lane < TILE_R) {
#pragma unroll
    for (int k = 0; k < K_; ++k) {
      float v = asum[k];
      v += __shfl_xor(v, 1);
      v += __shfl_xor(v, 2);
      v += __shfl_xor(v, 4);
      v += __shfl_xor(v, 8);
      v += __shfl_xor(v, 16);
      asum[k] = v;
    }
    if (lane == 0) {
      float* ap = asum_part + blk * K_;
#pragma unroll
      for (int k = 0; k < K_; ++k) ap[k] = asum[k];
    }
  }
}

// k2a: 4 blocks per batch -> reduce chunks, subtract asum*centers, partial sq
template <int NCHUNK_T>
__global__ __launch_bounds__(256) void k2a(
    const float* __restrict__ ax_part, const float* __restrict__ asum_part,
    const float* __restrict__ centers, float* __restrict__ pbuf,
    float* __restrict__ sqpart) {
  const int b = blockIdx.x >> 2;
  const int q = blockIdx.x & 3;
  const int tid = threadIdx.x;
  __shared__ float s_as[K_];
  __shared__ float s_sq[4];
  if (tid < K_) {
    float s = 0.f;
    for (int c = 0; c < NCHUNK_T; ++c) s += asum_part[(b * NCHUNK_T + c) * K_ + tid];
    s_as[tid] = s;
  }
  __syncthreads();
  const int idx = q * 1024 + tid * 4;
  float4 s = {0.f, 0.f, 0.f, 0.f};
  const float* base = ax_part + (size_t)b * NCHUNK_T * (K_ * D_) + idx;
  for (int c = 0; c < NCHUNK_T; ++c) {
    const float4 v = *(const float4*)(base + (size_t)c * (K_ * D_));
    s.x += v.x; s.y += v.y; s.z += v.z; s.w += v.w;
  }
  const int k = idx >> 9;
  const float a = s_as[k];
  const float4 cv = *(const float4*)(centers + idx);
  float4 p;
  p.x = s.x - a * cv.x; p.y = s.y - a * cv.y;
  p.z = s.z - a * cv.z; p.w = s.w - a * cv.w;
  *(float4*)(pbuf + (size_t)b * (K_ * D_) + idx) = p;
  float sq = p.x * p.x + p.y * p.y + p.z * p.z + p.w * p.w;
#pragma unroll
  for (int m = 32; m; m >>= 1) sq += __shfl_xor(sq, m);
  if ((tid & 63) == 0) s_sq[tid >> 6] = sq;
  __syncthreads();
  if (tid == 0) sqpart[blockIdx.x] = (s_sq[0] + s_sq[1]) + (s_sq[2] + s_sq[3]);
}

// k2b: normalize (pbuf is L2/L3-hot, 1MB)
__global__ __launch_bounds__(1024) void k2b(const float* __restrict__ pbuf,
                                            const float* __restrict__ sqpart,
                                            float* __restrict__ out) {
  const int b = blockIdx.x;
  const float tot =
      (sqpart[b * 4] + sqpart[b * 4 + 1]) + (sqpart[b * 4 + 2] + sqpart[b * 4 + 3]);
  const float invn = 1.0f / fmaxf(__builtin_sqrtf(tot), 1e-12f);
  const int idx = threadIdx.x * 4;
  const float4 p = *(const float4*)(pbuf + (size_t)b * (K_ * D_) + idx);
  *(float4*)(out + (size_t)b * (K_ * D_) + idx) =
      (float4){p.x * invn, p.y * invn, p.z * invn, p.w * invn};
}

// legacy single-kernel finalize (smallest-workspace fallback)
template <int NCHUNK_T>
__global__ __launch_bounds__(1024) void k2_old(
    const float* __restrict__ ax_part, const float* __restrict__ asum_part,
    const float* __restrict__ centers, float* __restrict__ out) {
  const int b = blockIdx.x;
  const int tid = threadIdx.x;
  const int wave = tid >> 6;
  const int lane = tid & 63;
  __shared__ float s_asum[K_];
  __shared__ float s_sq[16];
  if (tid < K_) {
    float s = 0.f;
    for (int c = 0; c < NCHUNK_T; ++c) s += asum_part[(b * NCHUNK_T + c) * K_ + tid];
    s_asum[tid] = s;
  }
  __syncthreads();
  const int NPT = (K_ * D_) / 1024;
  float pooled[NPT];
  float sq = 0.f;
  const float* base = ax_part + (size_t)b * NCHUNK_T * (K_ * D_);
#pragma unroll
  for (int i = 0; i < NPT; ++i) {
    const int idx = tid + i * 1024;
    float v = 0.f;
    for (int c = 0; c < NCHUNK_T; ++c) v += base[(size_t)c * (K_ * D_) + idx];
    v -= s_asum[idx >> 9] * centers[idx];
    pooled[i] = v;
    sq = fmaf(v, v, sq);
  }
#pragma unroll
  for (int m = 32; m; m >>= 1) sq += __shfl_xor(sq, m);
  if (lane == 0) s_sq[wave] = sq;
  __syncthreads();
  float tot = 0.f;
#pragma unroll
  for (int wv = 0; wv < 16; ++wv) tot += s_sq[wv];
  const float invn = 1.0f / fmaxf(__builtin_sqrtf(tot), 1e-12f);
#pragma unroll
  for (int i = 0; i < NPT; ++i)
    out[(size_t)b * (K_ * D_) + tid + i * 1024] = pooled[i] * invn;
}

extern "C" void kernel_launch(void* const* d_in, const int* in_sizes, int n_in,
                              void* d_out, int out_size, void* d_ws, size_t ws_size,
                              hipStream_t stream) {
  (void)in_sizes; (void)n_in; (void)out_size;
  const float* x = (const float*)d_in[0];
  const float* centers = (const float*)d_in[1];
  const float* attn_w = (const float*)d_in[2];
  const float* attn_b = (const float*)d_in[3];
  float* out = (float*)d_out;

  const size_t KD = (size_t)K_ * D_;
  auto need = [&](int n) {
    return (size_t)B_ * n * KD * 4 + (size_t)B_ * n * K_ * 4 +
           (size_t)B_ * KD * 4 + (size_t)B_ * 4 * 4;
  };

  if (ws_size >= need(16)) {
    float* ax = (float*)d_ws;
    float* as = ax + (size_t)B_ * 16 * KD;
    float* pb = as + (size_t)B_ * 16 * K_;
    float* sp = pb + (size_t)B_ * KD;
    k1_accum<16><<<B_ * 16, THREADS, 0, stream>>>(x, attn_w, attn_b, ax, as);
    k2a<16><<<B_ * 4, 256, 0, stream>>>(ax, as, centers, pb, sp);
    k2b<<<B_, 1024, 0, stream>>>(pb, sp, out);
  } else if (ws_size >= need(8)) {
    float* ax = (float*)d_ws;
    float* as = ax + (size_t)B_ * 8 * KD;
    float* pb = as + (size_t)B_ * 8 * K_;
    float* sp = pb + (size_t)B_ * KD;
    k1_accum<8><<<B_ * 8, THREADS, 0, stream>>>(x, attn_w, attn_b, ax, as);
    k2a<8><<<B_ * 4, 256, 0, stream>>>(ax, as, centers, pb, sp);
    k2b<<<B_, 1024, 0, stream>>>(pb, sp, out);
  } else {
    float* ax = (float*)d_ws;
    float* as = ax + (size_t)B_ * 8 * KD;
    k1_accum<8><<<B_ * 8, THREADS, 0, stream>>>(x, attn_w, attn_b, ax, as);
    k2_old<8><<<B_, 1024, 0, stream>>>(ax, as, centers, out);
  }
}

// Round 27
// 56.393 us; speedup vs baseline: 1.0885x; 1.0885x over previous
//
#include <hip/hip_runtime.h>

typedef float v2f __attribute__((ext_vector_type(2)));
typedef float v4f __attribute__((ext_vector_type(4)));
typedef __fp16 h2 __attribute__((ext_vector_type(2)));
typedef __fp16 h4 __attribute__((ext_vector_type(4)));

#define B_ 64
#define T_ 2048
#define D_ 512
#define K_ 8
#define THREADS 256
#define TILE_R 32
#define XPITCH 520   // f16 pitch: 512 + 8 pad
#define LGP 9        // logits pitch (f32)
#define APITCH 12    // a-table pitch (f32)
#define LOG2E 1.44269504088896340736f

// Raw barrier discipline (T3/T4): __syncthreads() drains vmcnt(0) before
// s_barrier -- keeps prefetch loads in flight across barriers instead.
#define LGKM0 asm volatile("s_waitcnt lgkmcnt(0)" ::: "memory")
#define BARRIER __builtin_amdgcn_s_barrier()
#define PIN __builtin_amdgcn_sched_barrier(0)

__device__ __forceinline__ float dev_exp2(float v) { return __builtin_amdgcn_exp2f(v); }
__device__ __forceinline__ h2 pack2(float a, float b) { return __builtin_amdgcn_cvt_pkrtz(a, b); }

// Round 27: FINAL -- exact revert to R22/R25 (55.7/56.4us, session best).
// Occupancy curve fully mapped: 2 blocks/CU unconstrained = best;
// 3/CU (R26, 61.4) and 4/CU (R24, 81.5) both regress via VGPR pressure;
// TILE_R=64 (R23, 74.6) spills. Structure: MFMA pass1 (hoisted B-frags),
// lane-local softmax, VALU pass2, counted-vmcnt raw-barrier pipeline,
// NCHUNK=8. k1 ~49us vs 38.3us traffic floor; residual = per-tile serial
// logits->softmax->pool chain (12 structural variants failed to remove it).
template <int NCHUNK_T>
__global__ __launch_bounds__(THREADS) void k1_accum(
    const float* __restrict__ x, const float* __restrict__ attn_w,
    const float* __restrict__ attn_b, float* __restrict__ ax_part,
    float* __restrict__ asum_part) {
  constexpr int RPC = T_ / NCHUNK_T;
  constexpr int TILES = RPC / TILE_R;  // 8

  const int blk = blockIdx.x;
  const int b = blk / NCHUNK_T;
  const int chunk = blk % NCHUNK_T;
  const int tid = threadIdx.x;
  const int wave = tid >> 6;
  const int lane = tid & 63;

  __shared__ __align__(16) __fp16 xt[TILE_R * XPITCH];  // 33.3 KB
  __shared__ float lg[4 * TILE_R * LGP];                // 4.6 KB
  __shared__ __align__(16) float at[TILE_R * APITCH];   // 1.5 KB
  __shared__ float bt[K_];

  if (tid < K_) bt[tid] = attn_b[tid] * LOG2E;

  // MFMA lane constants (layout verified on-silicon R13/R18/R20):
  //   A[m][k]: m=lane&15, k=(lane>>4)*4+i ; B[k][n]: n=lane&15, same k
  //   C[m][n]: n=lane&15, m=(lane>>4)*4+j
  const int m16 = lane & 15;
  const int kgrp = lane >> 4;
  const int koff = wave * 128 + kgrp * 4;  // wave owns a 128-d K-quarter
  const __fp16* arow0 = xt + m16 * XPITCH + koff;
  const __fp16* arow1 = xt + (16 + m16) * XPITCH + koff;

  const int d0p2 = wave * 128 + lane * 2;  // pass2 d-pair ownership

  v2f acc[K_];
#pragma unroll
  for (int k = 0; k < K_; ++k) acc[k] = (v2f){0.f, 0.f};
  float asum[K_];
#pragma unroll
  for (int k = 0; k < K_; ++k) asum[k] = 0.f;

  const float* xbase = x + ((size_t)b * T_ + (size_t)chunk * RPC) * (size_t)D_;
  const int t4 = tid << 2;

  float4 f0, f1, f2, f3, f4, f5, f6, f7, f8, f9, f10, f11, f12, f13, f14, f15;
#define LOADT(tt)                                                    \
  do {                                                               \
    const float* s_ = xbase + (size_t)(tt) * TILE_R * D_ + t4;       \
    f0 = *(const float4*)(s_ + 0 * 1024);                            \
    f1 = *(const float4*)(s_ + 1 * 1024);                            \
    f2 = *(const float4*)(s_ + 2 * 1024);                            \
    f3 = *(const float4*)(s_ + 3 * 1024);                            \
    f4 = *(const float4*)(s_ + 4 * 1024);                            \
    f5 = *(const float4*)(s_ + 5 * 1024);                            \
    f6 = *(const float4*)(s_ + 6 * 1024);                            \
    f7 = *(const float4*)(s_ + 7 * 1024);                            \
    f8 = *(const float4*)(s_ + 8 * 1024);                            \
    f9 = *(const float4*)(s_ + 9 * 1024);                            \
    f10 = *(const float4*)(s_ + 10 * 1024);                          \
    f11 = *(const float4*)(s_ + 11 * 1024);                          \
    f12 = *(const float4*)(s_ + 12 * 1024);                          \
    f13 = *(const float4*)(s_ + 13 * 1024);                          \
    f14 = *(const float4*)(s_ + 14 * 1024);                          \
    f15 = *(const float4*)(s_ + 15 * 1024);                          \
  } while (0)
#define WRT1(i, F)                                                   \
  do {                                                               \
    const int g_ = (i)*1024 + t4;                                    \
    const h2 lo_ = pack2(F.x, F.y), hi_ = pack2(F.z, F.w);           \
    h4 v_;                                                           \
    v_[0] = lo_[0]; v_[1] = lo_[1]; v_[2] = hi_[0]; v_[3] = hi_[1];  \
    *(h4*)(xt + (g_ >> 9) * XPITCH + (g_ & 511)) = v_;               \
  } while (0)
#define WRITET()                                                     \
  do {                                                               \
    WRT1(0, f0); WRT1(1, f1); WRT1(2, f2); WRT1(3, f3);              \
    WRT1(4, f4); WRT1(5, f5); WRT1(6, f6); WRT1(7, f7);              \
    WRT1(8, f8); WRT1(9, f9); WRT1(10, f10); WRT1(11, f11);          \
    WRT1(12, f12); WRT1(13, f13); WRT1(14, f14); WRT1(15, f15);      \
  } while (0)

  // prologue: stage tile0; B-frags from GLOBAL (W L2-hot, once per block);
  // issue tile1 (stays in flight across barriers, un-drained)
  LOADT(0);
  WRITET();
  h4 bf[8];
  {
    const int wrow = (m16 < K_ ? m16 : (K_ - 1));  // clamp pad cols
    const float* wg = attn_w + wrow * D_ + koff;
#pragma unroll
    for (int s = 0; s < 8; ++s) {
      const float4 g = *(const float4*)(wg + s * 16);
      const h2 lo = pack2(g.x * LOG2E, g.y * LOG2E);
      const h2 hi = pack2(g.z * LOG2E, g.w * LOG2E);
      bf[s][0] = lo[0]; bf[s][1] = lo[1]; bf[s][2] = hi[0]; bf[s][3] = hi[1];
    }
  }
  LOADT(1);
  PIN;  // pin tile1 issue point
  LGKM0;
  BARRIER;  // xt(0) + bt visible; tile1 loads in flight

#pragma unroll
  for (int t = 0; t < TILES; ++t) {
    // ---- pass1: logits = X·W^T via MFMA (A from xt, B from regs)
    {
      v4f c0 = {0.f, 0.f, 0.f, 0.f}, c1 = {0.f, 0.f, 0.f, 0.f};
#pragma unroll
      for (int s = 0; s < 8; ++s) {
        const h4 a0 = *(const h4*)(arow0 + s * 16);
        const h4 a1 = *(const h4*)(arow1 + s * 16);
        c0 = __builtin_amdgcn_mfma_f32_16x16x16f16(a0, bf[s], c0, 0, 0, 0);
        c1 = __builtin_amdgcn_mfma_f32_16x16x16f16(a1, bf[s], c1, 0, 0, 0);
      }
      if (m16 < K_) {
        const int base = (wave * TILE_R + kgrp * 4) * LGP + m16;
#pragma unroll
        for (int j = 0; j < 4; ++j) {
          lg[base + j * LGP] = c0[j];
          lg[base + (16 + j) * LGP] = c1[j];
        }
      }
    }
    LGKM0;
    BARRIER;  // lg visible

    // ---- softmax: lane-per-row (exp2 domain, no max-sub: logits ~N(0,1),
    //      fp32-safe; ratio identical). asum accumulated per owning lane.
    if (wave == 0 && lane < TILE_R) {
      float e[K_];
      float tot = 0.f;
#pragma unroll
      for (int k = 0; k < K_; ++k) {
        const float l = ((lg[(0 * TILE_R + lane) * LGP + k] +
                          lg[(1 * TILE_R + lane) * LGP + k]) +
                         (lg[(2 * TILE_R + lane) * LGP + k] +
                          lg[(3 * TILE_R + lane) * LGP + k])) + bt[k];
        e[k] = dev_exp2(l);
        tot += e[k];
      }
      const float inv = __builtin_amdgcn_rcpf(tot);
      float4* ad = (float4*)(at + lane * APITCH);
      ad[0] = (float4){e[0] * inv, e[1] * inv, e[2] * inv, e[3] * inv};
      ad[1] = (float4){e[4] * inv, e[5] * inv, e[6] * inv, e[7] * inv};
#pragma unroll
      for (int k = 0; k < K_; ++k) asum[k] += e[k] * inv;
    }
    LGKM0;
    BARRIER;  // at visible

    // ---- pass2: acc[k] += a[r][k] * x[r][d-pair]; a broadcast, x b32
#pragma unroll 4
    for (int rr = 0; rr < TILE_R; ++rr) {
      const float4 alo = *(const float4*)(at + rr * APITCH);
      const float4 ahi = *(const float4*)(at + rr * APITCH + 4);
      const h2 xp = *(const h2*)(xt + rr * XPITCH + d0p2);
      const v2f xv = {(float)xp[0], (float)xp[1]};
      acc[0] += (v2f){alo.x, alo.x} * xv;
      acc[1] += (v2f){alo.y, alo.y} * xv;
      acc[2] += (v2f){alo.z, alo.z} * xv;
      acc[3] += (v2f){alo.w, alo.w} * xv;
      acc[4] += (v2f){ahi.x, ahi.x} * xv;
      acc[5] += (v2f){ahi.y, ahi.y} * xv;
      acc[6] += (v2f){ahi.z, ahi.z} * xv;
      acc[7] += (v2f){ahi.w, ahi.w} * xv;
    }
    LGKM0;
    BARRIER;  // all waves done reading xt(t)

    // ---- drain tile t+1 into xt (loads issued a full iter ago: covered);
    //      issue tile t+2 (covered by next iter's pass1..pass2)
    if (t + 1 < TILES) {
      WRITET();
      if (t + 2 < TILES) {
        LOADT(t + 2);
        PIN;
      }
      LGKM0;
      BARRIER;  // xt(t+1) visible
    }
  }
#undef LOADT
#undef WRT1
#undef WRITET

  // ---- write per-chunk partials
  float* outp = ax_part + (size_t)blk * (K_ * D_);
#pragma unroll
  for (int k = 0; k < K_; ++k) *(v2f*)(outp + k * D_ + d0p2) = acc[k];
  // asum: reduce across the 32 row-owning lanes of wave 0
  if (wave == 0 && lane < TILE_R) {
#pragma unroll
    for (int k = 0; k < K_; ++k) {
      float v = asum[k];
      v += __shfl_xor(v, 1);
      v += __shfl_xor(v, 2);
      v += __shfl_xor(v, 4);
      v += __shfl_xor(v, 8);
      v += __shfl_xor(v, 16);
      asum[k] = v;
    }
    if (lane == 0) {
      float* ap = asum_part + blk * K_;
#pragma unroll
      for (int k = 0; k < K_; ++k) ap[k] = asum[k];
    }
  }
}

// k2a: 4 blocks per batch -> reduce chunks, subtract asum*centers, partial sq
template <int NCHUNK_T>
__global__ __launch_bounds__(256) void k2a(
    const float* __restrict__ ax_part, const float* __restrict__ asum_part,
    const float* __restrict__ centers, float* __restrict__ pbuf,
    float* __restrict__ sqpart) {
  const int b = blockIdx.x >> 2;
  const int q = blockIdx.x & 3;
  const int tid = threadIdx.x;
  __shared__ float s_as[K_];
  __shared__ float s_sq[4];
  if (tid < K_) {
    float s = 0.f;
    for (int c = 0; c < NCHUNK_T; ++c) s += asum_part[(b * NCHUNK_T + c) * K_ + tid];
    s_as[tid] = s;
  }
  __syncthreads();
  const int idx = q * 1024 + tid * 4;
  float4 s = {0.f, 0.f, 0.f, 0.f};
  const float* base = ax_part + (size_t)b * NCHUNK_T * (K_ * D_) + idx;
  for (int c = 0; c < NCHUNK_T; ++c) {
    const float4 v = *(const float4*)(base + (size_t)c * (K_ * D_));
    s.x += v.x; s.y += v.y; s.z += v.z; s.w += v.w;
  }
  const int k = idx >> 9;
  const float a = s_as[k];
  const float4 cv = *(const float4*)(centers + idx);
  float4 p;
  p.x = s.x - a * cv.x; p.y = s.y - a * cv.y;
  p.z = s.z - a * cv.z; p.w = s.w - a * cv.w;
  *(float4*)(pbuf + (size_t)b * (K_ * D_) + idx) = p;
  float sq = p.x * p.x + p.y * p.y + p.z * p.z + p.w * p.w;
#pragma unroll
  for (int m = 32; m; m >>= 1) sq += __shfl_xor(sq, m);
  if ((tid & 63) == 0) s_sq[tid >> 6] = sq;
  __syncthreads();
  if (tid == 0) sqpart[blockIdx.x] = (s_sq[0] + s_sq[1]) + (s_sq[2] + s_sq[3]);
}

// k2b: normalize (pbuf is L2/L3-hot, 1MB)
__global__ __launch_bounds__(1024) void k2b(const float* __restrict__ pbuf,
                                            const float* __restrict__ sqpart,
                                            float* __restrict__ out) {
  const int b = blockIdx.x;
  const float tot =
      (sqpart[b * 4] + sqpart[b * 4 + 1]) + (sqpart[b * 4 + 2] + sqpart[b * 4 + 3]);
  const float invn = 1.0f / fmaxf(__builtin_sqrtf(tot), 1e-12f);
  const int idx = threadIdx.x * 4;
  const float4 p = *(const float4*)(pbuf + (size_t)b * (K_ * D_) + idx);
  *(float4*)(out + (size_t)b * (K_ * D_) + idx) =
      (float4){p.x * invn, p.y * invn, p.z * invn, p.w * invn};
}

// legacy single-kernel finalize (smallest-workspace fallback)
template <int NCHUNK_T>
__global__ __launch_bounds__(1024) void k2_old(
    const float* __restrict__ ax_part, const float* __restrict__ asum_part,
    const float* __restrict__ centers, float* __restrict__ out) {
  const int b = blockIdx.x;
  const int tid = threadIdx.x;
  const int wave = tid >> 6;
  const int lane = tid & 63;
  __shared__ float s_asum[K_];
  __shared__ float s_sq[16];
  if (tid < K_) {
    float s = 0.f;
    for (int c = 0; c < NCHUNK_T; ++c) s += asum_part[(b * NCHUNK_T + c) * K_ + tid];
    s_asum[tid] = s;
  }
  __syncthreads();
  const int NPT = (K_ * D_) / 1024;
  float pooled[NPT];
  float sq = 0.f;
  const float* base = ax_part + (size_t)b * NCHUNK_T * (K_ * D_);
#pragma unroll
  for (int i = 0; i < NPT; ++i) {
    const int idx = tid + i * 1024;
    float v = 0.f;
    for (int c = 0; c < NCHUNK_T; ++c) v += base[(size_t)c * (K_ * D_) + idx];
    v -= s_asum[idx >> 9] * centers[idx];
    pooled[i] = v;
    sq = fmaf(v, v, sq);
  }
#pragma unroll
  for (int m = 32; m; m >>= 1) sq += __shfl_xor(sq, m);
  if (lane == 0) s_sq[wave] = sq;
  __syncthreads();
  float tot = 0.f;
#pragma unroll
  for (int wv = 0; wv < 16; ++wv) tot += s_sq[wv];
  const float invn = 1.0f / fmaxf(__builtin_sqrtf(tot), 1e-12f);
#pragma unroll
  for (int i = 0; i < NPT; ++i)
    out[(size_t)b * (K_ * D_) + tid + i * 1024] = pooled[i] * invn;
}

extern "C" void kernel_launch(void* const* d_in, const int* in_sizes, int n_in,
                              void* d_out, int out_size, void* d_ws, size_t ws_size,
                              hipStream_t stream) {
  (void)in_sizes; (void)n_in; (void)out_size;
  const float* x = (const float*)d_in[0];
  const float* centers = (const float*)d_in[1];
  const float* attn_w = (const float*)d_in[2];
  const float* attn_b = (const float*)d_in[3];
  float* out = (float*)d_out;

  const size_t KD = (size_t)K_ * D_;
  const size_t need8 = (size_t)B_ * 8 * KD * 4 + (size_t)B_ * 8 * K_ * 4 +
                       (size_t)B_ * KD * 4 + (size_t)B_ * 4 * 4;

  if (ws_size >= need8) {
    float* ax = (float*)d_ws;
    float* as = ax + (size_t)B_ * 8 * KD;
    float* pb = as + (size_t)B_ * 8 * K_;
    float* sp = pb + (size_t)B_ * KD;
    k1_accum<8><<<B_ * 8, THREADS, 0, stream>>>(x, attn_w, attn_b, ax, as);
    k2a<8><<<B_ * 4, 256, 0, stream>>>(ax, as, centers, pb, sp);
    k2b<<<B_, 1024, 0, stream>>>(pb, sp, out);
  } else {
    float* ax = (float*)d_ws;
    float* as = ax + (size_t)B_ * 8 * KD;
    k1_accum<8><<<B_ * 8, THREADS, 0, stream>>>(x, attn_w, attn_b, ax, as);
    k2_old<8><<<B_, 1024, 0, stream>>>(ax, as, centers, out);
  }
}